// Round 1
// baseline (571.392 us; speedup 1.0000x reference)
//
#include <hip/hip_runtime.h>
#include <hip/hip_bf16.h>

#define T_TOK 2048
#define DDIM  1024
#define NEXP  8
#define FDIM  4096

typedef __attribute__((ext_vector_type(8))) short bf16x8;
typedef __attribute__((ext_vector_type(4))) float f32x4;

__device__ __forceinline__ unsigned short f2b(float f) {
  union { float f; unsigned u; } v; v.f = f;
  unsigned r = v.u + 0x7FFF + ((v.u >> 16) & 1);  // round-to-nearest-even
  return (unsigned short)(r >> 16);
}
__device__ __forceinline__ float b2f(unsigned short s) {
  union { unsigned u; float f; } v; v.u = ((unsigned)s) << 16;
  return v.f;
}

// ---------------- router: logits, top-2, softmax, compaction ----------------
__global__ void router_kernel(const float* __restrict__ x, const float* __restrict__ Wr,
                              int* __restrict__ cnt, int* __restrict__ tok,
                              float* __restrict__ prb) {
  int t = (blockIdx.x * blockDim.x + threadIdx.x) >> 6;  // one wave per token
  int lane = threadIdx.x & 63;
  if (t >= T_TOK) return;
  const float* xr = x + (size_t)t * DDIM;
  float acc[NEXP];
#pragma unroll
  for (int e = 0; e < NEXP; ++e) acc[e] = 0.f;
#pragma unroll
  for (int i = 0; i < 4; ++i) {
    int d0 = lane * 16 + i * 4;
    float4 xv = *reinterpret_cast<const float4*>(xr + d0);
#pragma unroll
    for (int j = 0; j < 4; ++j) {
      float xd = (&xv.x)[j];
      float4 w0 = *reinterpret_cast<const float4*>(Wr + (size_t)(d0 + j) * NEXP);
      float4 w1 = *reinterpret_cast<const float4*>(Wr + (size_t)(d0 + j) * NEXP + 4);
      acc[0] += xd * w0.x; acc[1] += xd * w0.y; acc[2] += xd * w0.z; acc[3] += xd * w0.w;
      acc[4] += xd * w1.x; acc[5] += xd * w1.y; acc[6] += xd * w1.z; acc[7] += xd * w1.w;
    }
  }
#pragma unroll
  for (int off = 32; off >= 1; off >>= 1)
#pragma unroll
    for (int e = 0; e < NEXP; ++e) acc[e] += __shfl_down(acc[e], off);
  if (lane == 0) {
    float v0 = -1e30f, v1 = -1e30f; int i0 = 0, i1 = 0;
#pragma unroll
    for (int e = 0; e < NEXP; ++e) {
      float v = acc[e];
      if (v > v0)      { v1 = v0; i1 = i0; v0 = v; i0 = e; }
      else if (v > v1) { v1 = v; i1 = e; }
    }
    float e1 = __expf(v1 - v0);
    float p0 = 1.f / (1.f + e1);
    float p1 = e1 * p0;
    int s0 = atomicAdd(&cnt[i0], 1);
    tok[i0 * T_TOK + s0] = t; prb[i0 * T_TOK + s0] = p0;
    int s1 = atomicAdd(&cnt[i1], 1);
    tok[i1 * T_TOK + s1] = t; prb[i1 * T_TOK + s1] = p1;
  }
}

// ---------------- GEMM1: h/g = gather(x) @ W  (bf16 MFMA, 128x128 tile) -----
__global__ __launch_bounds__(256, 2)
void gemm1_kernel(const float* __restrict__ x, const float* __restrict__ W,
                  const int* __restrict__ cnt, const int* __restrict__ tok,
                  unsigned short* __restrict__ oh) {
  const int e = blockIdx.z;
  const int cn = cnt[e];
  const int r0 = blockIdx.y * 128;
  if (r0 >= cn) return;
  const int n0 = blockIdx.x * 128;
  int off = 0;
#pragma unroll
  for (int i = 0; i < NEXP; ++i) off += (i < e) ? cnt[i] : 0;
  const float* We = W + (size_t)e * DDIM * FDIM;

  __shared__ __align__(16) unsigned short sA[128 * 64];
  __shared__ __align__(16) unsigned short sB[128 * 64];

  const int tid = threadIdx.x;
  const int lane = tid & 63;
  const int wid = tid >> 6;
  const int wm = wid >> 1, wn = wid & 1;

  // A staging: thread -> (row, 32-elem chunk)
  const int ar = tid >> 1;
  const int ac = (tid & 1) * 32;
  int slot = r0 + ar;
  int tk = tok[e * T_TOK + (slot < cn ? slot : cn - 1)];
  const float* xrow = x + (size_t)tk * DDIM + ac;

  // B staging (transpose): lane owns one f-row of the [n=f][k=d] LDS tile
  const int bf = (wid & 1) * 64 + lane;
  const int bd0 = (wid >> 1) * 32;
  const float* wcol = We + (size_t)n0 + bf;

  f32x4 acc[4][4];
#pragma unroll
  for (int i = 0; i < 4; ++i)
#pragma unroll
    for (int j = 0; j < 4; ++j) acc[i][j] = (f32x4){0.f, 0.f, 0.f, 0.f};

  for (int k0 = 0; k0 < DDIM; k0 += 64) {
    __syncthreads();
    {  // stage A: 32 fp32 -> bf16, swizzled b128 writes
      const float* src = xrow + k0;
      int swz = (ar & 7) << 3;
#pragma unroll
      for (int j = 0; j < 4; ++j) {
        float4 v0 = *reinterpret_cast<const float4*>(src + j * 8);
        float4 v1 = *reinterpret_cast<const float4*>(src + j * 8 + 4);
        bf16x8 p;
        p[0] = (short)f2b(v0.x); p[1] = (short)f2b(v0.y);
        p[2] = (short)f2b(v0.z); p[3] = (short)f2b(v0.w);
        p[4] = (short)f2b(v1.x); p[5] = (short)f2b(v1.y);
        p[6] = (short)f2b(v1.z); p[7] = (short)f2b(v1.w);
        *reinterpret_cast<bf16x8*>(&sA[ar * 64 + ((ac + j * 8) ^ swz)]) = p;
      }
    }
    {  // stage B transposed: coalesced dword loads along f, b128 writes along k
      int swz = (bf & 7) << 3;
#pragma unroll
      for (int jj = 0; jj < 4; ++jj) {
        bf16x8 p;
#pragma unroll
        for (int j = 0; j < 8; ++j)
          p[j] = (short)f2b(wcol[(size_t)(k0 + bd0 + jj * 8 + j) * FDIM]);
        *reinterpret_cast<bf16x8*>(&sB[bf * 64 + ((bd0 + jj * 8) ^ swz)]) = p;
      }
    }
    __syncthreads();
#pragma unroll
    for (int kk = 0; kk < 2; ++kk) {
      bf16x8 a[4], b[4];
      int kc = kk * 32 + (lane >> 4) * 8;
#pragma unroll
      for (int m = 0; m < 4; ++m) {
        int row = wm * 64 + m * 16 + (lane & 15);
        a[m] = *reinterpret_cast<const bf16x8*>(&sA[row * 64 + (kc ^ ((row & 7) << 3))]);
      }
#pragma unroll
      for (int n = 0; n < 4; ++n) {
        int row = wn * 64 + n * 16 + (lane & 15);
        b[n] = *reinterpret_cast<const bf16x8*>(&sB[row * 64 + (kc ^ ((row & 7) << 3))]);
      }
#pragma unroll
      for (int m = 0; m < 4; ++m)
#pragma unroll
        for (int n = 0; n < 4; ++n)
          acc[m][n] = __builtin_amdgcn_mfma_f32_16x16x32_bf16(a[m], b[n], acc[m][n], 0, 0, 0);
    }
  }
  // epilogue: store bf16 rows (masked to valid slots)
#pragma unroll
  for (int m = 0; m < 4; ++m)
#pragma unroll
    for (int j = 0; j < 4; ++j) {
      int rloc = wm * 64 + m * 16 + (lane >> 4) * 4 + j;
      int s = r0 + rloc;
      if (s < cn) {
        unsigned short* orow = oh + (size_t)(off + s) * FDIM + n0 + wn * 64 + (lane & 15);
#pragma unroll
        for (int n = 0; n < 4; ++n) orow[n * 16] = f2b(acc[m][n][j]);
      }
    }
}

// ---------------- SiLU(h) * g -> act (bf16) ----------------
__global__ void silu_kernel(const unsigned short* __restrict__ h,
                            const unsigned short* __restrict__ g,
                            unsigned short* __restrict__ a) {
  size_t i = ((size_t)blockIdx.x * 256 + threadIdx.x) * 8;
  bf16x8 hv = *reinterpret_cast<const bf16x8*>(h + i);
  bf16x8 gv = *reinterpret_cast<const bf16x8*>(g + i);
  bf16x8 o;
#pragma unroll
  for (int j = 0; j < 8; ++j) {
    float hf = b2f((unsigned short)hv[j]);
    float gf = b2f((unsigned short)gv[j]);
    float s = hf / (1.f + __expf(-hf));
    o[j] = (short)f2b(s * gf);
  }
  *reinterpret_cast<bf16x8*>(a + i) = o;
}

// ---------------- GEMM2: y = act @ W2, atomic scatter * prob ----------------
__global__ __launch_bounds__(256, 2)
void gemm2_kernel(const unsigned short* __restrict__ act, const float* __restrict__ W2,
                  const int* __restrict__ cnt, const int* __restrict__ tok,
                  const float* __restrict__ prb, float* __restrict__ out) {
  const int e = blockIdx.z;
  const int cn = cnt[e];
  const int r0 = blockIdx.y * 128;
  if (r0 >= cn) return;
  const int n0 = blockIdx.x * 128;
  int off = 0;
#pragma unroll
  for (int i = 0; i < NEXP; ++i) off += (i < e) ? cnt[i] : 0;
  const float* We = W2 + (size_t)e * FDIM * DDIM;

  __shared__ __align__(16) unsigned short sA[128 * 64];
  __shared__ __align__(16) unsigned short sB[128 * 64];

  const int tid = threadIdx.x;
  const int lane = tid & 63;
  const int wid = tid >> 6;
  const int wm = wid >> 1, wn = wid & 1;

  const int ar = tid >> 1;
  const int ac = (tid & 1) * 32;
  const unsigned short* arow = act + (size_t)(off + r0 + ar) * FDIM + ac;

  const int bd = (wid & 1) * 64 + lane;   // d (output col) row of [n=d][k=f] tile
  const int bf0 = (wid >> 1) * 32;
  const float* wcol = We + (size_t)n0 + bd;

  f32x4 acc[4][4];
#pragma unroll
  for (int i = 0; i < 4; ++i)
#pragma unroll
    for (int j = 0; j < 4; ++j) acc[i][j] = (f32x4){0.f, 0.f, 0.f, 0.f};

  for (int k0 = 0; k0 < FDIM; k0 += 64) {
    __syncthreads();
    {  // stage A (already bf16)
      int swz = (ar & 7) << 3;
#pragma unroll
      for (int j = 0; j < 4; ++j) {
        bf16x8 p = *reinterpret_cast<const bf16x8*>(arow + k0 + j * 8);
        *reinterpret_cast<bf16x8*>(&sA[ar * 64 + ((ac + j * 8) ^ swz)]) = p;
      }
    }
    {  // stage B transposed
      int swz = (bd & 7) << 3;
#pragma unroll
      for (int jj = 0; jj < 4; ++jj) {
        bf16x8 p;
#pragma unroll
        for (int j = 0; j < 8; ++j)
          p[j] = (short)f2b(wcol[(size_t)(k0 + bf0 + jj * 8 + j) * DDIM]);
        *reinterpret_cast<bf16x8*>(&sB[bd * 64 + ((bf0 + jj * 8) ^ swz)]) = p;
      }
    }
    __syncthreads();
#pragma unroll
    for (int kk = 0; kk < 2; ++kk) {
      bf16x8 a[4], b[4];
      int kc = kk * 32 + (lane >> 4) * 8;
#pragma unroll
      for (int m = 0; m < 4; ++m) {
        int row = wm * 64 + m * 16 + (lane & 15);
        a[m] = *reinterpret_cast<const bf16x8*>(&sA[row * 64 + (kc ^ ((row & 7) << 3))]);
      }
#pragma unroll
      for (int n = 0; n < 4; ++n) {
        int row = wn * 64 + n * 16 + (lane & 15);
        b[n] = *reinterpret_cast<const bf16x8*>(&sB[row * 64 + (kc ^ ((row & 7) << 3))]);
      }
#pragma unroll
      for (int m = 0; m < 4; ++m)
#pragma unroll
        for (int n = 0; n < 4; ++n)
          acc[m][n] = __builtin_amdgcn_mfma_f32_16x16x32_bf16(a[m], b[n], acc[m][n], 0, 0, 0);
    }
  }
  // epilogue: weighted atomic scatter (exactly 2 commutative adds per cell)
#pragma unroll
  for (int m = 0; m < 4; ++m)
#pragma unroll
    for (int j = 0; j < 4; ++j) {
      int rloc = wm * 64 + m * 16 + (lane >> 4) * 4 + j;
      int s = r0 + rloc;
      if (s < cn) {
        int tkn = tok[e * T_TOK + s];
        float p = prb[e * T_TOK + s];
        float* orow = out + (size_t)tkn * DDIM + n0 + wn * 64 + (lane & 15);
#pragma unroll
        for (int n = 0; n < 4; ++n) atomicAdd(&orow[n * 16], p * acc[m][n][j]);
      }
    }
}

extern "C" void kernel_launch(void* const* d_in, const int* in_sizes, int n_in,
                              void* d_out, int out_size, void* d_ws, size_t ws_size,
                              hipStream_t stream) {
  const float* x  = (const float*)d_in[0];
  const float* Wr = (const float*)d_in[1];
  const float* W1 = (const float*)d_in[2];
  const float* W2 = (const float*)d_in[3];
  const float* W3 = (const float*)d_in[4];
  float* out = (float*)d_out;

  char* ws = (char*)d_ws;
  int*   cnt = (int*)ws;                        // 32 B
  int*   tok = (int*)(ws + 1024);               // 64 KB
  float* prb = (float*)(ws + 1024 + 65536);     // 64 KB
  const size_t ROWS = 4096 + 128;               // pad for partial tiles
  unsigned short* h_ws = (unsigned short*)(ws + 256 * 1024);
  unsigned short* g_ws = h_ws + ROWS * (size_t)FDIM;
  unsigned short* a_ws = g_ws + ROWS * (size_t)FDIM;

  hipMemsetAsync(cnt, 0, NEXP * sizeof(int), stream);
  hipMemsetAsync(d_out, 0, (size_t)out_size * sizeof(float), stream);

  router_kernel<<<T_TOK / 4, 256, 0, stream>>>(x, Wr, cnt, tok, prb);
  gemm1_kernel<<<dim3(FDIM / 128, 16, NEXP), 256, 0, stream>>>(x, W1, cnt, tok, h_ws);
  gemm1_kernel<<<dim3(FDIM / 128, 16, NEXP), 256, 0, stream>>>(x, W3, cnt, tok, g_ws);
  silu_kernel<<<(4096u * 4096u) / (8 * 256), 256, 0, stream>>>(h_ws, g_ws, a_ws);
  gemm2_kernel<<<dim3(DDIM / 128, 16, NEXP), 256, 0, stream>>>(a_ws, W2, cnt, tok, prb, out);
}

// Round 2
// 377.170 us; speedup vs baseline: 1.5149x; 1.5149x over previous
//
#include <hip/hip_runtime.h>
#include <hip/hip_bf16.h>

#define T_TOK 2048
#define DDIM  1024
#define NEXP  8
#define FDIM  4096

typedef __attribute__((ext_vector_type(8))) short bf16x8;
typedef __attribute__((ext_vector_type(4))) float f32x4;

__device__ __forceinline__ unsigned short f2b(float f) {
  union { float f; unsigned u; } v; v.f = f;
  unsigned r = v.u + 0x7FFF + ((v.u >> 16) & 1);  // round-to-nearest-even
  return (unsigned short)(r >> 16);
}
__device__ __forceinline__ float b2f(unsigned short s) {
  union { unsigned u; float f; } v; v.u = ((unsigned)s) << 16;
  return v.f;
}

__device__ __forceinline__ void gl16(const unsigned short* g, unsigned short* l) {
  __builtin_amdgcn_global_load_lds(
      (const __attribute__((address_space(1))) unsigned int*)(const void*)g,
      (__attribute__((address_space(3))) unsigned int*)(void*)l, 16, 0, 0);
}

// ---------------- router: logits, top-2, softmax, compaction ----------------
__global__ void router_kernel(const float* __restrict__ x, const float* __restrict__ Wr,
                              int* __restrict__ cnt, int* __restrict__ tok,
                              float* __restrict__ prb) {
  int t = (blockIdx.x * blockDim.x + threadIdx.x) >> 6;  // one wave per token
  int lane = threadIdx.x & 63;
  if (t >= T_TOK) return;
  const float* xr = x + (size_t)t * DDIM;
  float acc[NEXP];
#pragma unroll
  for (int e = 0; e < NEXP; ++e) acc[e] = 0.f;
#pragma unroll
  for (int i = 0; i < 4; ++i) {
    int d0 = lane * 16 + i * 4;
    float4 xv = *reinterpret_cast<const float4*>(xr + d0);
#pragma unroll
    for (int j = 0; j < 4; ++j) {
      float xd = (&xv.x)[j];
      float4 w0 = *reinterpret_cast<const float4*>(Wr + (size_t)(d0 + j) * NEXP);
      float4 w1 = *reinterpret_cast<const float4*>(Wr + (size_t)(d0 + j) * NEXP + 4);
      acc[0] += xd * w0.x; acc[1] += xd * w0.y; acc[2] += xd * w0.z; acc[3] += xd * w0.w;
      acc[4] += xd * w1.x; acc[5] += xd * w1.y; acc[6] += xd * w1.z; acc[7] += xd * w1.w;
    }
  }
#pragma unroll
  for (int off = 32; off >= 1; off >>= 1)
#pragma unroll
    for (int e = 0; e < NEXP; ++e) acc[e] += __shfl_down(acc[e], off);
  if (lane == 0) {
    float v0 = -1e30f, v1 = -1e30f; int i0 = 0, i1 = 0;
#pragma unroll
    for (int e = 0; e < NEXP; ++e) {
      float v = acc[e];
      if (v > v0)      { v1 = v0; i1 = i0; v0 = v; i0 = e; }
      else if (v > v1) { v1 = v; i1 = e; }
    }
    float e1 = __expf(v1 - v0);
    float p0 = 1.f / (1.f + e1);
    float p1 = e1 * p0;
    int s0 = atomicAdd(&cnt[i0], 1);
    tok[i0 * T_TOK + s0] = t; prb[i0 * T_TOK + s0] = p0;
    int s1 = atomicAdd(&cnt[i1], 1);
    tok[i1 * T_TOK + s1] = t; prb[i1 * T_TOK + s1] = p1;
  }
}

// ---------------- pre-pass: x fp32 -> bf16 ----------------
__global__ void cvt_x_kernel(const float* __restrict__ in, unsigned short* __restrict__ o) {
  size_t i = ((size_t)blockIdx.x * 256 + threadIdx.x) * 8;
  float4 a = *reinterpret_cast<const float4*>(in + i);
  float4 b = *reinterpret_cast<const float4*>(in + i + 4);
  bf16x8 p;
  p[0] = (short)f2b(a.x); p[1] = (short)f2b(a.y); p[2] = (short)f2b(a.z); p[3] = (short)f2b(a.w);
  p[4] = (short)f2b(b.x); p[5] = (short)f2b(b.y); p[6] = (short)f2b(b.z); p[7] = (short)f2b(b.w);
  *reinterpret_cast<bf16x8*>(o + i) = p;
}

// ---------------- pre-pass: per-expert transpose fp32 [R][C] -> bf16 [C][R] --
__global__ void transpose_kernel(const float* __restrict__ in, unsigned short* __restrict__ o,
                                 int R, int C) {
  const int e = blockIdx.z;
  const float* src = in + (size_t)e * R * C;
  unsigned short* dst = o + (size_t)e * R * C;
  __shared__ float t[64][65];
  int r0 = blockIdx.y * 64, c0 = blockIdx.x * 64;
  int tid = threadIdx.x;
  int lr = tid >> 4, lc = (tid & 15) * 4;
#pragma unroll
  for (int i = 0; i < 4; ++i) {
    float4 v = *reinterpret_cast<const float4*>(src + (size_t)(r0 + lr + i * 16) * C + c0 + lc);
    t[lr + i * 16][lc] = v.x; t[lr + i * 16][lc + 1] = v.y;
    t[lr + i * 16][lc + 2] = v.z; t[lr + i * 16][lc + 3] = v.w;
  }
  __syncthreads();
  int oc = tid >> 3;
  int orr = (tid & 7) * 8;
#pragma unroll
  for (int p = 0; p < 2; ++p) {
    int c = oc + p * 32;
    bf16x8 ov;
#pragma unroll
    for (int j = 0; j < 8; ++j) ov[j] = (short)f2b(t[orr + j][c]);
    *reinterpret_cast<bf16x8*>(dst + (size_t)(c0 + c) * R + r0 + orr) = ov;
  }
}

// ---------------- fast GEMM1: h/act = gather(xb) @ Wt^T (bf16, gload_lds) ----
template <int FUSE>
__global__ __launch_bounds__(256, 2)
void gemm1f_kernel(const unsigned short* __restrict__ xb, const unsigned short* __restrict__ Wt,
                   const int* __restrict__ cnt, const int* __restrict__ tok,
                   unsigned short* __restrict__ oh) {
  const int e = blockIdx.z;
  const int cn = cnt[e];
  const int r0 = blockIdx.y * 128;
  if (r0 >= cn) return;
  const int n0 = blockIdx.x * 128;
  int off = 0;
#pragma unroll
  for (int i = 0; i < NEXP; ++i) off += (i < e) ? cnt[i] : 0;

  __shared__ __align__(16) unsigned short sA[128 * 64];
  __shared__ __align__(16) unsigned short sB[128 * 64];

  const int tid = threadIdx.x;
  const int lane = tid & 63;
  const int wid = tid >> 6;
  const int wm = wid >> 1, wn = wid & 1;

  // per-lane staging sources; wave w owns 1KB chunks 4w..4w+3; row=(chunk)*8+lane/8
  const unsigned short* asrc[4];
  const unsigned short* bsrc[4];
#pragma unroll
  for (int i = 0; i < 4; ++i) {
    int row = (4 * wid + i) * 8 + (lane >> 3);
    int slot = r0 + row; if (slot >= cn) slot = cn - 1;
    int tk = tok[e * T_TOK + slot];
    int sl = (lane & 7) ^ (row & 7);   // pre-swizzled source slot (inverse of read swz)
    asrc[i] = xb + (size_t)tk * DDIM + sl * 8;
    bsrc[i] = Wt + ((size_t)e * FDIM + n0 + row) * DDIM + sl * 8;
  }

  f32x4 acc[4][4];
#pragma unroll
  for (int i = 0; i < 4; ++i)
#pragma unroll
    for (int j = 0; j < 4; ++j) acc[i][j] = (f32x4){0.f, 0.f, 0.f, 0.f};

  for (int k0 = 0; k0 < DDIM; k0 += 64) {
    __syncthreads();
#pragma unroll
    for (int i = 0; i < 4; ++i) {
      gl16(asrc[i] + k0, &sA[(4 * wid + i) * 512]);
      gl16(bsrc[i] + k0, &sB[(4 * wid + i) * 512]);
    }
    __syncthreads();
#pragma unroll
    for (int kk = 0; kk < 2; ++kk) {
      bf16x8 a[4], b[4];
      int kc8 = kk * 4 + (lane >> 4);
#pragma unroll
      for (int m = 0; m < 4; ++m) {
        int row = wm * 64 + m * 16 + (lane & 15);
        a[m] = *reinterpret_cast<const bf16x8*>(&sA[row * 64 + ((kc8 ^ (row & 7)) * 8)]);
      }
#pragma unroll
      for (int n = 0; n < 4; ++n) {
        int row = wn * 64 + n * 16 + (lane & 15);
        b[n] = *reinterpret_cast<const bf16x8*>(&sB[row * 64 + ((kc8 ^ (row & 7)) * 8)]);
      }
#pragma unroll
      for (int m = 0; m < 4; ++m)
#pragma unroll
        for (int n = 0; n < 4; ++n)
          acc[m][n] = __builtin_amdgcn_mfma_f32_16x16x32_bf16(a[m], b[n], acc[m][n], 0, 0, 0);
    }
  }
#pragma unroll
  for (int m = 0; m < 4; ++m)
#pragma unroll
    for (int j = 0; j < 4; ++j) {
      int rloc = wm * 64 + m * 16 + (lane >> 4) * 4 + j;
      int s = r0 + rloc;
      if (s < cn) {
        unsigned short* orow = oh + (size_t)(off + s) * FDIM + n0 + wn * 64 + (lane & 15);
#pragma unroll
        for (int n = 0; n < 4; ++n) {
          float v = acc[m][n][j];
          if (FUSE) {  // this is the W3 (up) gemm: act = silu(h) * g, in place over h
            float h = b2f(orow[n * 16]);
            float sg = h / (1.f + __expf(-h));
            v = sg * v;
          }
          orow[n * 16] = f2b(v);
        }
      }
    }
}

// ---------------- fast GEMM2: out += p * act @ W2t^T (split-K=2, atomics) ----
__global__ __launch_bounds__(256, 2)
void gemm2f_kernel(const unsigned short* __restrict__ act, const unsigned short* __restrict__ W2t,
                   const int* __restrict__ cnt, const int* __restrict__ tok,
                   const float* __restrict__ prb, float* __restrict__ out) {
  const int e = blockIdx.z >> 1;
  const int sp = blockIdx.z & 1;
  const int cn = cnt[e];
  const int r0 = blockIdx.y * 128;
  if (r0 >= cn) return;
  const int n0 = blockIdx.x * 128;
  int off = 0;
#pragma unroll
  for (int i = 0; i < NEXP; ++i) off += (i < e) ? cnt[i] : 0;

  __shared__ __align__(16) unsigned short sA[128 * 64];
  __shared__ __align__(16) unsigned short sB[128 * 64];

  const int tid = threadIdx.x;
  const int lane = tid & 63;
  const int wid = tid >> 6;
  const int wm = wid >> 1, wn = wid & 1;

  const unsigned short* asrc[4];
  const unsigned short* bsrc[4];
#pragma unroll
  for (int i = 0; i < 4; ++i) {
    int row = (4 * wid + i) * 8 + (lane >> 3);
    int sl = (lane & 7) ^ (row & 7);
    asrc[i] = act + (size_t)(off + r0 + row) * FDIM + sl * 8;  // pad rows exist; masked later
    bsrc[i] = W2t + ((size_t)e * DDIM + n0 + row) * FDIM + sl * 8;
  }

  f32x4 acc[4][4];
#pragma unroll
  for (int i = 0; i < 4; ++i)
#pragma unroll
    for (int j = 0; j < 4; ++j) acc[i][j] = (f32x4){0.f, 0.f, 0.f, 0.f};

  const int kbeg = sp * (FDIM / 2), kend = kbeg + (FDIM / 2);
  for (int k0 = kbeg; k0 < kend; k0 += 64) {
    __syncthreads();
#pragma unroll
    for (int i = 0; i < 4; ++i) {
      gl16(asrc[i] + k0, &sA[(4 * wid + i) * 512]);
      gl16(bsrc[i] + k0, &sB[(4 * wid + i) * 512]);
    }
    __syncthreads();
#pragma unroll
    for (int kk = 0; kk < 2; ++kk) {
      bf16x8 a[4], b[4];
      int kc8 = kk * 4 + (lane >> 4);
#pragma unroll
      for (int m = 0; m < 4; ++m) {
        int row = wm * 64 + m * 16 + (lane & 15);
        a[m] = *reinterpret_cast<const bf16x8*>(&sA[row * 64 + ((kc8 ^ (row & 7)) * 8)]);
      }
#pragma unroll
      for (int n = 0; n < 4; ++n) {
        int row = wn * 64 + n * 16 + (lane & 15);
        b[n] = *reinterpret_cast<const bf16x8*>(&sB[row * 64 + ((kc8 ^ (row & 7)) * 8)]);
      }
#pragma unroll
      for (int m = 0; m < 4; ++m)
#pragma unroll
        for (int n = 0; n < 4; ++n)
          acc[m][n] = __builtin_amdgcn_mfma_f32_16x16x32_bf16(a[m], b[n], acc[m][n], 0, 0, 0);
    }
  }
#pragma unroll
  for (int m = 0; m < 4; ++m)
#pragma unroll
    for (int j = 0; j < 4; ++j) {
      int rloc = wm * 64 + m * 16 + (lane >> 4) * 4 + j;
      int s = r0 + rloc;
      if (s < cn) {
        int tkn = tok[e * T_TOK + s];
        float p = prb[e * T_TOK + s];
        float* orow = out + (size_t)tkn * DDIM + n0 + wn * 64 + (lane & 15);
#pragma unroll
        for (int n = 0; n < 4; ++n) atomicAdd(&orow[n * 16], p * acc[m][n][j]);
      }
    }
}

// ======================= round-1 fallback kernels ===========================
__global__ __launch_bounds__(256, 2)
void gemm1_kernel(const float* __restrict__ x, const float* __restrict__ W,
                  const int* __restrict__ cnt, const int* __restrict__ tok,
                  unsigned short* __restrict__ oh) {
  const int e = blockIdx.z;
  const int cn = cnt[e];
  const int r0 = blockIdx.y * 128;
  if (r0 >= cn) return;
  const int n0 = blockIdx.x * 128;
  int off = 0;
#pragma unroll
  for (int i = 0; i < NEXP; ++i) off += (i < e) ? cnt[i] : 0;
  const float* We = W + (size_t)e * DDIM * FDIM;
  __shared__ __align__(16) unsigned short sA[128 * 64];
  __shared__ __align__(16) unsigned short sB[128 * 64];
  const int tid = threadIdx.x;
  const int lane = tid & 63;
  const int wid = tid >> 6;
  const int wm = wid >> 1, wn = wid & 1;
  const int ar = tid >> 1;
  const int ac = (tid & 1) * 32;
  int slot = r0 + ar;
  int tk = tok[e * T_TOK + (slot < cn ? slot : cn - 1)];
  const float* xrow = x + (size_t)tk * DDIM + ac;
  const int bf = (wid & 1) * 64 + lane;
  const int bd0 = (wid >> 1) * 32;
  const float* wcol = We + (size_t)n0 + bf;
  f32x4 acc[4][4];
#pragma unroll
  for (int i = 0; i < 4; ++i)
#pragma unroll
    for (int j = 0; j < 4; ++j) acc[i][j] = (f32x4){0.f, 0.f, 0.f, 0.f};
  for (int k0 = 0; k0 < DDIM; k0 += 64) {
    __syncthreads();
    {
      const float* src = xrow + k0;
      int swz = (ar & 7) << 3;
#pragma unroll
      for (int j = 0; j < 4; ++j) {
        float4 v0 = *reinterpret_cast<const float4*>(src + j * 8);
        float4 v1 = *reinterpret_cast<const float4*>(src + j * 8 + 4);
        bf16x8 p;
        p[0] = (short)f2b(v0.x); p[1] = (short)f2b(v0.y);
        p[2] = (short)f2b(v0.z); p[3] = (short)f2b(v0.w);
        p[4] = (short)f2b(v1.x); p[5] = (short)f2b(v1.y);
        p[6] = (short)f2b(v1.z); p[7] = (short)f2b(v1.w);
        *reinterpret_cast<bf16x8*>(&sA[ar * 64 + ((ac + j * 8) ^ swz)]) = p;
      }
    }
    {
      int swz = (bf & 7) << 3;
#pragma unroll
      for (int jj = 0; jj < 4; ++jj) {
        bf16x8 p;
#pragma unroll
        for (int j = 0; j < 8; ++j)
          p[j] = (short)f2b(wcol[(size_t)(k0 + bd0 + jj * 8 + j) * FDIM]);
        *reinterpret_cast<bf16x8*>(&sB[bf * 64 + ((bd0 + jj * 8) ^ swz)]) = p;
      }
    }
    __syncthreads();
#pragma unroll
    for (int kk = 0; kk < 2; ++kk) {
      bf16x8 a[4], b[4];
      int kc = kk * 32 + (lane >> 4) * 8;
#pragma unroll
      for (int m = 0; m < 4; ++m) {
        int row = wm * 64 + m * 16 + (lane & 15);
        a[m] = *reinterpret_cast<const bf16x8*>(&sA[row * 64 + (kc ^ ((row & 7) << 3))]);
      }
#pragma unroll
      for (int n = 0; n < 4; ++n) {
        int row = wn * 64 + n * 16 + (lane & 15);
        b[n] = *reinterpret_cast<const bf16x8*>(&sB[row * 64 + (kc ^ ((row & 7) << 3))]);
      }
#pragma unroll
      for (int m = 0; m < 4; ++m)
#pragma unroll
        for (int n = 0; n < 4; ++n)
          acc[m][n] = __builtin_amdgcn_mfma_f32_16x16x32_bf16(a[m], b[n], acc[m][n], 0, 0, 0);
    }
  }
#pragma unroll
  for (int m = 0; m < 4; ++m)
#pragma unroll
    for (int j = 0; j < 4; ++j) {
      int rloc = wm * 64 + m * 16 + (lane >> 4) * 4 + j;
      int s = r0 + rloc;
      if (s < cn) {
        unsigned short* orow = oh + (size_t)(off + s) * FDIM + n0 + wn * 64 + (lane & 15);
#pragma unroll
        for (int n = 0; n < 4; ++n) orow[n * 16] = f2b(acc[m][n][j]);
      }
    }
}

__global__ void silu_kernel(const unsigned short* __restrict__ h,
                            const unsigned short* __restrict__ g,
                            unsigned short* __restrict__ a) {
  size_t i = ((size_t)blockIdx.x * 256 + threadIdx.x) * 8;
  bf16x8 hv = *reinterpret_cast<const bf16x8*>(h + i);
  bf16x8 gv = *reinterpret_cast<const bf16x8*>(g + i);
  bf16x8 o;
#pragma unroll
  for (int j = 0; j < 8; ++j) {
    float hf = b2f((unsigned short)hv[j]);
    float gf = b2f((unsigned short)gv[j]);
    float s = hf / (1.f + __expf(-hf));
    o[j] = (short)f2b(s * gf);
  }
  *reinterpret_cast<bf16x8*>(a + i) = o;
}

__global__ __launch_bounds__(256, 2)
void gemm2_kernel(const unsigned short* __restrict__ act, const float* __restrict__ W2,
                  const int* __restrict__ cnt, const int* __restrict__ tok,
                  const float* __restrict__ prb, float* __restrict__ out) {
  const int e = blockIdx.z;
  const int cn = cnt[e];
  const int r0 = blockIdx.y * 128;
  if (r0 >= cn) return;
  const int n0 = blockIdx.x * 128;
  int off = 0;
#pragma unroll
  for (int i = 0; i < NEXP; ++i) off += (i < e) ? cnt[i] : 0;
  const float* We = W2 + (size_t)e * FDIM * DDIM;
  __shared__ __align__(16) unsigned short sA[128 * 64];
  __shared__ __align__(16) unsigned short sB[128 * 64];
  const int tid = threadIdx.x;
  const int lane = tid & 63;
  const int wid = tid >> 6;
  const int wm = wid >> 1, wn = wid & 1;
  const int ar = tid >> 1;
  const int ac = (tid & 1) * 32;
  const unsigned short* arow = act + (size_t)(off + r0 + ar) * FDIM + ac;
  const int bd = (wid & 1) * 64 + lane;
  const int bf0 = (wid >> 1) * 32;
  const float* wcol = We + (size_t)n0 + bd;
  f32x4 acc[4][4];
#pragma unroll
  for (int i = 0; i < 4; ++i)
#pragma unroll
    for (int j = 0; j < 4; ++j) acc[i][j] = (f32x4){0.f, 0.f, 0.f, 0.f};
  for (int k0 = 0; k0 < FDIM; k0 += 64) {
    __syncthreads();
    {
      int swz = (ar & 7) << 3;
#pragma unroll
      for (int j = 0; j < 4; ++j) {
        bf16x8 p = *reinterpret_cast<const bf16x8*>(arow + k0 + j * 8);
        *reinterpret_cast<bf16x8*>(&sA[ar * 64 + ((ac + j * 8) ^ swz)]) = p;
      }
    }
    {
      int swz = (bd & 7) << 3;
#pragma unroll
      for (int jj = 0; jj < 4; ++jj) {
        bf16x8 p;
#pragma unroll
        for (int j = 0; j < 8; ++j)
          p[j] = (short)f2b(wcol[(size_t)(k0 + bf0 + jj * 8 + j) * DDIM]);
        *reinterpret_cast<bf16x8*>(&sB[bd * 64 + ((bf0 + jj * 8) ^ swz)]) = p;
      }
    }
    __syncthreads();
#pragma unroll
    for (int kk = 0; kk < 2; ++kk) {
      bf16x8 a[4], b[4];
      int kc = kk * 32 + (lane >> 4) * 8;
#pragma unroll
      for (int m = 0; m < 4; ++m) {
        int row = wm * 64 + m * 16 + (lane & 15);
        a[m] = *reinterpret_cast<const bf16x8*>(&sA[row * 64 + (kc ^ ((row & 7) << 3))]);
      }
#pragma unroll
      for (int n = 0; n < 4; ++n) {
        int row = wn * 64 + n * 16 + (lane & 15);
        b[n] = *reinterpret_cast<const bf16x8*>(&sB[row * 64 + (kc ^ ((row & 7) << 3))]);
      }
#pragma unroll
      for (int m = 0; m < 4; ++m)
#pragma unroll
        for (int n = 0; n < 4; ++n)
          acc[m][n] = __builtin_amdgcn_mfma_f32_16x16x32_bf16(a[m], b[n], acc[m][n], 0, 0, 0);
    }
  }
#pragma unroll
  for (int m = 0; m < 4; ++m)
#pragma unroll
    for (int j = 0; j < 4; ++j) {
      int rloc = wm * 64 + m * 16 + (lane >> 4) * 4 + j;
      int s = r0 + rloc;
      if (s < cn) {
        int tkn = tok[e * T_TOK + s];
        float p = prb[e * T_TOK + s];
        float* orow = out + (size_t)tkn * DDIM + n0 + wn * 64 + (lane & 15);
#pragma unroll
        for (int n = 0; n < 4; ++n) atomicAdd(&orow[n * 16], p * acc[m][n][j]);
      }
    }
}

// ============================================================================
extern "C" void kernel_launch(void* const* d_in, const int* in_sizes, int n_in,
                              void* d_out, int out_size, void* d_ws, size_t ws_size,
                              hipStream_t stream) {
  const float* x  = (const float*)d_in[0];
  const float* Wr = (const float*)d_in[1];
  const float* W1 = (const float*)d_in[2];
  const float* W2 = (const float*)d_in[3];
  const float* W3 = (const float*)d_in[4];
  float* out = (float*)d_out;

  char* ws = (char*)d_ws;
  int*   cnt = (int*)ws;
  int*   tok = (int*)(ws + 1024);
  float* prb = (float*)(ws + 1024 + 65536);

  const size_t SLAB = (size_t)NEXP * DDIM * FDIM * 2;         // 64 MB bf16
  const size_t HB   = (size_t)(4096 + 128) * FDIM * 2;        // 34.6 MB
  const size_t NEED = 256 * 1024 + (size_t)T_TOK * DDIM * 2 + 3 * SLAB + HB;

  hipMemsetAsync(cnt, 0, NEXP * sizeof(int), stream);
  hipMemsetAsync(d_out, 0, (size_t)out_size * sizeof(float), stream);
  router_kernel<<<T_TOK / 4, 256, 0, stream>>>(x, Wr, cnt, tok, prb);

  if (ws_size >= NEED) {
    // -------- fast path: bf16 pre-convert + transposed weights --------
    unsigned short* xb  = (unsigned short*)(ws + 256 * 1024);
    unsigned short* W1t = xb + (size_t)T_TOK * DDIM;
    unsigned short* W3t = W1t + SLAB / 2;
    unsigned short* W2t = W3t + SLAB / 2;
    unsigned short* hb  = W2t + SLAB / 2;   // h, then act in place

    cvt_x_kernel<<<(T_TOK * DDIM) / (256 * 8), 256, 0, stream>>>(x, xb);
    transpose_kernel<<<dim3(FDIM / 64, DDIM / 64, NEXP), 256, 0, stream>>>(W1, W1t, DDIM, FDIM);
    transpose_kernel<<<dim3(FDIM / 64, DDIM / 64, NEXP), 256, 0, stream>>>(W3, W3t, DDIM, FDIM);
    transpose_kernel<<<dim3(DDIM / 64, FDIM / 64, NEXP), 256, 0, stream>>>(W2, W2t, FDIM, DDIM);

    gemm1f_kernel<0><<<dim3(FDIM / 128, 16, NEXP), 256, 0, stream>>>(xb, W1t, cnt, tok, hb);
    gemm1f_kernel<1><<<dim3(FDIM / 128, 16, NEXP), 256, 0, stream>>>(xb, W3t, cnt, tok, hb);
    gemm2f_kernel<<<dim3(DDIM / 128, 16, NEXP * 2), 256, 0, stream>>>(hb, W2t, cnt, tok, prb, out);
  } else {
    // -------- fallback: round-1 path (needs ~104 MB) --------
    const size_t ROWS = 4096 + 128;
    unsigned short* h_ws = (unsigned short*)(ws + 256 * 1024);
    unsigned short* g_ws = h_ws + ROWS * (size_t)FDIM;
    unsigned short* a_ws = g_ws + ROWS * (size_t)FDIM;
    gemm1_kernel<<<dim3(FDIM / 128, 16, NEXP), 256, 0, stream>>>(x, W1, cnt, tok, h_ws);
    gemm1_kernel<<<dim3(FDIM / 128, 16, NEXP), 256, 0, stream>>>(x, W3, cnt, tok, g_ws);
    silu_kernel<<<(4096u * 4096u) / (8 * 256), 256, 0, stream>>>(h_ws, g_ws, a_ws);
    gemm2_kernel<<<dim3(DDIM / 128, 16, NEXP), 256, 0, stream>>>(a_ws, W2, cnt, tok, prb, out);
  }
}

// Round 3
// 307.678 us; speedup vs baseline: 1.8571x; 1.2259x over previous
//
#include <hip/hip_runtime.h>
#include <hip/hip_bf16.h>

#define T_TOK 2048
#define DDIM  1024
#define NEXP  8
#define FDIM  4096

typedef __attribute__((ext_vector_type(8))) short bf16x8;
typedef __attribute__((ext_vector_type(4))) float f32x4;

#define SBW(n) ((((n) >> 3) ^ (n)) & 7)

__device__ __forceinline__ unsigned short f2b(float f) {
  union { float f; unsigned u; } v; v.f = f;
  unsigned r = v.u + 0x7FFF + ((v.u >> 16) & 1);  // RNE
  return (unsigned short)(r >> 16);
}
__device__ __forceinline__ float b2f(unsigned short s) {
  union { unsigned u; float f; } v; v.u = ((unsigned)s) << 16;
  return v.f;
}
// pack 2 fp32 -> 2 bf16 (RNE) in one instruction
__device__ __forceinline__ unsigned cvtpk(float lo, float hi) {
  unsigned r;
  asm("v_cvt_pk_bf16_f32 %0, %1, %2" : "=v"(r) : "v"(lo), "v"(hi));
  return r;
}

__device__ __forceinline__ void gl16(const unsigned short* g, unsigned short* l) {
  __builtin_amdgcn_global_load_lds(
      (const __attribute__((address_space(1))) unsigned int*)(const void*)g,
      (__attribute__((address_space(3))) unsigned int*)(void*)l, 16, 0, 0);
}

// ---------------- router ----------------
__global__ void router_kernel(const float* __restrict__ x, const float* __restrict__ Wr,
                              int* __restrict__ cnt, int* __restrict__ tok,
                              float* __restrict__ prb) {
  int t = (blockIdx.x * blockDim.x + threadIdx.x) >> 6;
  int lane = threadIdx.x & 63;
  if (t >= T_TOK) return;
  const float* xr = x + (size_t)t * DDIM;
  float acc[NEXP];
#pragma unroll
  for (int e = 0; e < NEXP; ++e) acc[e] = 0.f;
#pragma unroll
  for (int i = 0; i < 4; ++i) {
    int d0 = lane * 16 + i * 4;
    float4 xv = *reinterpret_cast<const float4*>(xr + d0);
#pragma unroll
    for (int j = 0; j < 4; ++j) {
      float xd = (&xv.x)[j];
      float4 w0 = *reinterpret_cast<const float4*>(Wr + (size_t)(d0 + j) * NEXP);
      float4 w1 = *reinterpret_cast<const float4*>(Wr + (size_t)(d0 + j) * NEXP + 4);
      acc[0] += xd * w0.x; acc[1] += xd * w0.y; acc[2] += xd * w0.z; acc[3] += xd * w0.w;
      acc[4] += xd * w1.x; acc[5] += xd * w1.y; acc[6] += xd * w1.z; acc[7] += xd * w1.w;
    }
  }
#pragma unroll
  for (int off = 32; off >= 1; off >>= 1)
#pragma unroll
    for (int e = 0; e < NEXP; ++e) acc[e] += __shfl_down(acc[e], off);
  if (lane == 0) {
    float v0 = -1e30f, v1 = -1e30f; int i0 = 0, i1 = 0;
#pragma unroll
    for (int e = 0; e < NEXP; ++e) {
      float v = acc[e];
      if (v > v0)      { v1 = v0; i1 = i0; v0 = v; i0 = e; }
      else if (v > v1) { v1 = v; i1 = e; }
    }
    float e1 = __expf(v1 - v0);
    float p0 = 1.f / (1.f + e1);
    float p1 = e1 * p0;
    int s0 = atomicAdd(&cnt[i0], 1);
    tok[i0 * T_TOK + s0] = t; prb[i0 * T_TOK + s0] = p0;
    int s1 = atomicAdd(&cnt[i1], 1);
    tok[i1 * T_TOK + s1] = t; prb[i1 * T_TOK + s1] = p1;
  }
}

// ---------------- x fp32 -> bf16 ----------------
__global__ void cvt_x_kernel(const float* __restrict__ in, unsigned short* __restrict__ o) {
  size_t i = ((size_t)blockIdx.x * 256 + threadIdx.x) * 8;
  float4 a = *reinterpret_cast<const float4*>(in + i);
  float4 b = *reinterpret_cast<const float4*>(in + i + 4);
  bf16x8 p;
  p[0] = (short)f2b(a.x); p[1] = (short)f2b(a.y); p[2] = (short)f2b(a.z); p[3] = (short)f2b(a.w);
  p[4] = (short)f2b(b.x); p[5] = (short)f2b(b.y); p[6] = (short)f2b(b.z); p[7] = (short)f2b(b.w);
  *reinterpret_cast<bf16x8*>(o + i) = p;
}

// ======== fused GEMM1: act = silu(x@W1) * (x@W3), direct fp32 weights ========
// block tile 128m x 64n, 4 waves (2m x 2n), K-step 64.
__global__ __launch_bounds__(256, 2)
void gemm1ab_kernel(const unsigned short* __restrict__ xb,
                    const float* __restrict__ W1, const float* __restrict__ W3,
                    const int* __restrict__ cnt, const int* __restrict__ tok,
                    unsigned short* __restrict__ act) {
  const int e = blockIdx.z;
  const int cn = cnt[e];
  const int r0 = blockIdx.y * 128;
  if (r0 >= cn) return;
  const int n0 = blockIdx.x * 64;
  int off = 0;
#pragma unroll
  for (int i = 0; i < NEXP; ++i) off += (i < e) ? cnt[i] : 0;

  __shared__ __align__(16) unsigned short sA[128 * 64];
  __shared__ __align__(16) unsigned short sB1[64 * 64];
  __shared__ __align__(16) unsigned short sB3[64 * 64];

  const int tid = threadIdx.x;
  const int lane = tid & 63;
  const int wid = tid >> 6;
  const int wm = wid >> 1, wn = wid & 1;

  // A staging sources (bf16, gl16 direct, pre-swizzled per-lane source)
  const unsigned short* asrc[4];
#pragma unroll
  for (int i = 0; i < 4; ++i) {
    int row = (4 * wid + i) * 8 + (lane >> 3);
    int slot = r0 + row; if (slot >= cn) slot = cn - 1;
    int tk = tok[e * T_TOK + slot];
    int sl = (lane & 7) ^ (row & 7);
    asrc[i] = xb + (size_t)tk * DDIM + sl * 8;
  }

  // B staging: thread owns k-quad kq (4 rows) x 4 n-cols
  const int kq = tid >> 4;           // 0..15
  const int nc = (tid & 15) * 4;     // 0..60
  const float* b1p = W1 + ((size_t)e * DDIM + 4 * kq) * FDIM + n0 + nc;
  const float* b3p = W3 + ((size_t)e * DDIM + 4 * kq) * FDIM + n0 + nc;

  float4 r1[4], r3[4];
#pragma unroll
  for (int r = 0; r < 4; ++r) {
    r1[r] = *reinterpret_cast<const float4*>(b1p + (size_t)r * FDIM);
    r3[r] = *reinterpret_cast<const float4*>(b3p + (size_t)r * FDIM);
  }

  f32x4 ah[4][2], ag[4][2];
#pragma unroll
  for (int m = 0; m < 4; ++m)
#pragma unroll
    for (int n = 0; n < 2; ++n) { ah[m][n] = (f32x4){0,0,0,0}; ag[m][n] = (f32x4){0,0,0,0}; }

  for (int k0 = 0; k0 < DDIM; k0 += 64) {
    // stage B from regs (cvt_pk + transposed b64 writes, swizzled)
#pragma unroll
    for (int j = 0; j < 4; ++j) {
      int n = nc + j;
      int offB = n * 128 + (((kq >> 1) ^ SBW(n)) * 16) + (kq & 1) * 8;
      uint2 wv;
      wv.x = cvtpk((&r1[0].x)[j], (&r1[1].x)[j]);
      wv.y = cvtpk((&r1[2].x)[j], (&r1[3].x)[j]);
      *reinterpret_cast<uint2*>((char*)sB1 + offB) = wv;
      wv.x = cvtpk((&r3[0].x)[j], (&r3[1].x)[j]);
      wv.y = cvtpk((&r3[2].x)[j], (&r3[3].x)[j]);
      *reinterpret_cast<uint2*>((char*)sB3 + offB) = wv;
    }
#pragma unroll
    for (int i = 0; i < 4; ++i) gl16(asrc[i] + k0, &sA[(4 * wid + i) * 512]);
    __syncthreads();
    // prefetch next k-step's B into regs; latency hides under MFMA phase
    if (k0 + 64 < DDIM) {
#pragma unroll
      for (int r = 0; r < 4; ++r) {
        r1[r] = *reinterpret_cast<const float4*>(b1p + (size_t)(k0 + 64 + r) * FDIM);
        r3[r] = *reinterpret_cast<const float4*>(b3p + (size_t)(k0 + 64 + r) * FDIM);
      }
    }
#pragma unroll
    for (int kk = 0; kk < 2; ++kk) {
      int kc8 = kk * 4 + (lane >> 4);
      bf16x8 a[4], b1[2], b3[2];
#pragma unroll
      for (int m = 0; m < 4; ++m) {
        int row = wm * 64 + m * 16 + (lane & 15);
        a[m] = *reinterpret_cast<const bf16x8*>(&sA[row * 64 + ((kc8 ^ (row & 7)) * 8)]);
      }
#pragma unroll
      for (int n = 0; n < 2; ++n) {
        int rowb = wn * 32 + n * 16 + (lane & 15);
        int offb = rowb * 64 + ((kc8 ^ SBW(rowb)) * 8);
        b1[n] = *reinterpret_cast<const bf16x8*>(&sB1[offb]);
        b3[n] = *reinterpret_cast<const bf16x8*>(&sB3[offb]);
      }
#pragma unroll
      for (int m = 0; m < 4; ++m)
#pragma unroll
        for (int n = 0; n < 2; ++n) {
          ah[m][n] = __builtin_amdgcn_mfma_f32_16x16x32_bf16(a[m], b1[n], ah[m][n], 0, 0, 0);
          ag[m][n] = __builtin_amdgcn_mfma_f32_16x16x32_bf16(a[m], b3[n], ag[m][n], 0, 0, 0);
        }
    }
    __syncthreads();
  }
  // epilogue: act = silu(h) * g
#pragma unroll
  for (int m = 0; m < 4; ++m)
#pragma unroll
    for (int j = 0; j < 4; ++j) {
      int rloc = wm * 64 + m * 16 + (lane >> 4) * 4 + j;
      int s = r0 + rloc;
      if (s < cn) {
        unsigned short* orow = act + (size_t)(off + s) * FDIM + n0 + wn * 32 + (lane & 15);
#pragma unroll
        for (int n = 0; n < 2; ++n) {
          float hv = ah[m][n][j];
          float gv = ag[m][n][j];
          float sg = hv / (1.f + __expf(-hv));
          orow[n * 16] = f2b(sg * gv);
        }
      }
    }
}

// ======== GEMM2: out += p * act @ W2 (direct fp32 W2, split-K=4, atomics) ====
// block tile 128m x 128n, 4 waves (2m x 2n), K-step 64.
__global__ __launch_bounds__(256, 2)
void gemm2d_kernel(const unsigned short* __restrict__ act, const float* __restrict__ W2,
                   const int* __restrict__ cnt, const int* __restrict__ tok,
                   const float* __restrict__ prb, float* __restrict__ out) {
  const int e = blockIdx.z >> 2;
  const int sp = blockIdx.z & 3;
  const int cn = cnt[e];
  const int r0 = blockIdx.y * 128;
  if (r0 >= cn) return;
  const int n0 = blockIdx.x * 128;
  const int kbase = sp * (FDIM / 4);
  int off = 0;
#pragma unroll
  for (int i = 0; i < NEXP; ++i) off += (i < e) ? cnt[i] : 0;

  __shared__ __align__(16) unsigned short sA[128 * 64];
  __shared__ __align__(16) unsigned short sB[128 * 64];

  const int tid = threadIdx.x;
  const int lane = tid & 63;
  const int wid = tid >> 6;
  const int wm = wid >> 1, wn = wid & 1;

  const unsigned short* asrc[4];
#pragma unroll
  for (int i = 0; i < 4; ++i) {
    int row = (4 * wid + i) * 8 + (lane >> 3);
    int sl = (lane & 7) ^ (row & 7);
    asrc[i] = act + (size_t)(off + r0 + row) * FDIM + kbase + sl * 8;
  }

  const int kq = tid >> 4;          // 0..15
  const int nc = (tid & 15) * 8;    // 0..120
  const float* b2p = W2 + ((size_t)e * FDIM + kbase + 4 * kq) * DDIM + n0 + nc;

  float4 ra[4], rb[4];
#pragma unroll
  for (int r = 0; r < 4; ++r) {
    ra[r] = *reinterpret_cast<const float4*>(b2p + (size_t)r * DDIM);
    rb[r] = *reinterpret_cast<const float4*>(b2p + (size_t)r * DDIM + 4);
  }

  f32x4 acc[4][4];
#pragma unroll
  for (int m = 0; m < 4; ++m)
#pragma unroll
    for (int n = 0; n < 4; ++n) acc[m][n] = (f32x4){0,0,0,0};

  for (int k0 = 0; k0 < FDIM / 4; k0 += 64) {
#pragma unroll
    for (int j = 0; j < 8; ++j) {
      int n = nc + j;
      int offB = n * 128 + (((kq >> 1) ^ SBW(n)) * 16) + (kq & 1) * 8;
      uint2 wv;
      if (j < 4) {
        wv.x = cvtpk((&ra[0].x)[j], (&ra[1].x)[j]);
        wv.y = cvtpk((&ra[2].x)[j], (&ra[3].x)[j]);
      } else {
        wv.x = cvtpk((&rb[0].x)[j - 4], (&rb[1].x)[j - 4]);
        wv.y = cvtpk((&rb[2].x)[j - 4], (&rb[3].x)[j - 4]);
      }
      *reinterpret_cast<uint2*>((char*)sB + offB) = wv;
    }
#pragma unroll
    for (int i = 0; i < 4; ++i) gl16(asrc[i] + k0, &sA[(4 * wid + i) * 512]);
    __syncthreads();
    if (k0 + 64 < FDIM / 4) {
#pragma unroll
      for (int r = 0; r < 4; ++r) {
        ra[r] = *reinterpret_cast<const float4*>(b2p + (size_t)(k0 + 64 + r) * DDIM);
        rb[r] = *reinterpret_cast<const float4*>(b2p + (size_t)(k0 + 64 + r) * DDIM + 4);
      }
    }
#pragma unroll
    for (int kk = 0; kk < 2; ++kk) {
      int kc8 = kk * 4 + (lane >> 4);
      bf16x8 a[4], b[4];
#pragma unroll
      for (int m = 0; m < 4; ++m) {
        int row = wm * 64 + m * 16 + (lane & 15);
        a[m] = *reinterpret_cast<const bf16x8*>(&sA[row * 64 + ((kc8 ^ (row & 7)) * 8)]);
      }
#pragma unroll
      for (int n = 0; n < 4; ++n) {
        int rowb = wn * 64 + n * 16 + (lane & 15);
        b[n] = *reinterpret_cast<const bf16x8*>(&sB[rowb * 64 + ((kc8 ^ SBW(rowb)) * 8)]);
      }
#pragma unroll
      for (int m = 0; m < 4; ++m)
#pragma unroll
        for (int n = 0; n < 4; ++n)
          acc[m][n] = __builtin_amdgcn_mfma_f32_16x16x32_bf16(a[m], b[n], acc[m][n], 0, 0, 0);
    }
    __syncthreads();
  }
#pragma unroll
  for (int m = 0; m < 4; ++m)
#pragma unroll
    for (int j = 0; j < 4; ++j) {
      int rloc = wm * 64 + m * 16 + (lane >> 4) * 4 + j;
      int s = r0 + rloc;
      if (s < cn) {
        int tkn = tok[e * T_TOK + s];
        float p = prb[e * T_TOK + s];
        float* orow = out + (size_t)tkn * DDIM + n0 + wn * 64 + (lane & 15);
#pragma unroll
        for (int n = 0; n < 4; ++n) atomicAdd(&orow[n * 16], p * acc[m][n][j]);
      }
    }
}

// ============================================================================
extern "C" void kernel_launch(void* const* d_in, const int* in_sizes, int n_in,
                              void* d_out, int out_size, void* d_ws, size_t ws_size,
                              hipStream_t stream) {
  const float* x  = (const float*)d_in[0];
  const float* Wr = (const float*)d_in[1];
  const float* W1 = (const float*)d_in[2];
  const float* W2 = (const float*)d_in[3];
  const float* W3 = (const float*)d_in[4];
  float* out = (float*)d_out;

  char* ws = (char*)d_ws;
  int*   cnt = (int*)ws;                      // 32 B
  int*   tok = (int*)(ws + 1024);             // 64 KB
  float* prb = (float*)(ws + 1024 + 65536);   // 64 KB
  unsigned short* xb  = (unsigned short*)(ws + 256 * 1024);         // 4 MB
  unsigned short* act = xb + (size_t)T_TOK * DDIM;                  // 4224 x 4096 bf16

  hipMemsetAsync(cnt, 0, NEXP * sizeof(int), stream);
  hipMemsetAsync(d_out, 0, (size_t)out_size * sizeof(float), stream);

  router_kernel<<<T_TOK / 4, 256, 0, stream>>>(x, Wr, cnt, tok, prb);
  cvt_x_kernel<<<(T_TOK * DDIM) / (256 * 8), 256, 0, stream>>>(x, xb);
  gemm1ab_kernel<<<dim3(FDIM / 64, 16, NEXP), 256, 0, stream>>>(xb, W1, W3, cnt, tok, act);
  gemm2d_kernel<<<dim3(DDIM / 128, 16, NEXP * 4), 256, 0, stream>>>(act, W2, cnt, tok, prb, out);
}